// Round 4
// baseline (203.864 us; speedup 1.0000x reference)
//
#include <hip/hip_runtime.h>
#include <hip/hip_bf16.h>

// LSTM: B=4096, T=200, I=2, H=64, O=2
// grid = 1024 blocks x 256 threads (4 waves). Each block owns 4 batch rows ->
// 4 independent blocks per CU (4 waves/SIMD, each from a DIFFERENT block), so
// per-step barriers couple only 4 waves and the 4 blocks slide to hide dep
// chains. Wave w owns units [16w,16w+16); lane (grp,cidx) activates exactly
// one (row=grp, unit=16w+cidx) pair.
// A-frag trick: A'[p] = h[p>>2] (each h row duplicated 4x) => D reg r of
// group g equals batch row g for ALL r -> static a[0] extraction, no garbage.
// Activation algebra: gate scales folded into weights at load
// (i,f,o: -log2e ; g: 2*log2e), reciprocals merged:
//   c' = (c*P + (Eg-1)(1+Ef)) * rcp(P*(1+Ef)),  P = (1+Ei)(Eg+1)
//   h  = (Ec-1) * rcp((1+Eo)(Ec+1))
// => 5 exp + 2 rcp per unit-row (was 5+5).

#define B_ 4096
#define T_ 200

typedef _Float16 half8 __attribute__((ext_vector_type(8)));
typedef float f32x4 __attribute__((ext_vector_type(4)));

#define K1f 1.4426950408889634f   // log2(e)
#define K2f 2.8853900817779268f   // 2*log2(e)
#define ECLAMP 40.0f              // exp2 arg cap: keeps triple products < 2^127

__global__ __launch_bounds__(256, 4) void lstm_kernel(
    const float* __restrict__ x,     // [4096][200][2]
    const float* __restrict__ W_ih,  // [256][2]
    const float* __restrict__ W_hh,  // [256][64]
    const float* __restrict__ b_ih,  // [256]
    const float* __restrict__ b_hh,  // [256]
    const float* __restrict__ W_fc,  // [2][64]
    const float* __restrict__ b_fc,  // [2]
    float* __restrict__ out)         // [4096][2]
{
    __shared__ float xs[4][404];         // x tile, padded (broadcast reads, conflict-free)
    __shared__ _Float16 h16[2][4][76];   // double-buffered h; stride 152B -> max 2-way (free)
    __shared__ float wfc[130];           // W_fc (128) + b_fc (2)

    const int tid  = threadIdx.x;
    const int lane = tid & 63;
    const int w    = tid >> 6;      // wave = unit quadrant 0..3
    const int cidx = lane & 15;
    const int grp  = lane >> 4;
    const int r0   = blockIdx.x * 4;

    // ---- stage x tile (coalesced float4): 4 rows x 100 float4 ----
    for (int i4 = tid; i4 < 400; i4 += 256) {
        const int row = i4 / 100;
        const int j4  = i4 - row * 100;
        reinterpret_cast<float4*>(&xs[row][0])[j4] =
            reinterpret_cast<const float4*>(x + (size_t)(r0 + row) * 400)[j4];
    }
    // ---- zero h16 (both buffers incl. pad): 2*4*76 f16 = 304 dwords ----
    for (int i = tid; i < 304; i += 256)
        reinterpret_cast<unsigned int*>(&h16[0][0][0])[i] = 0u;
    if (tid < 130) wfc[tid] = (tid < 128) ? W_fc[tid] : b_fc[tid - 128];

    // ---- W_hh B-fragments (f16, PRE-SCALED per gate) + x-proj coeffs ----
    // B-frag layout for mfma_f32_16x16x32_f16: lane l -> col = l&15, k = (l>>4)*8 + e
    half8 bfrag[4][2];
    float wi0[4], wi1[4], bs[4];
    const int u = w * 16 + cidx;           // hidden unit owned by this lane
    #pragma unroll
    for (int m = 0; m < 4; ++m) {          // gate: 0=i,1=f,2=g,3=o (PyTorch order)
        const float sc = (m == 2) ? K2f : -K1f;
        const int g = m * 64 + u;
        wi0[m] = W_ih[g * 2 + 0] * sc;
        wi1[m] = W_ih[g * 2 + 1] * sc;
        bs[m]  = (b_ih[g] + b_hh[g]) * sc;
        #pragma unroll
        for (int kt = 0; kt < 2; ++kt) {
            const float* p = W_hh + g * 64 + kt * 32 + grp * 8;
            const float4 lo = reinterpret_cast<const float4*>(p)[0];
            const float4 hi = reinterpret_cast<const float4*>(p)[1];
            half8 f;
            f[0] = (_Float16)(lo.x * sc); f[1] = (_Float16)(lo.y * sc);
            f[2] = (_Float16)(lo.z * sc); f[3] = (_Float16)(lo.w * sc);
            f[4] = (_Float16)(hi.x * sc); f[5] = (_Float16)(hi.y * sc);
            f[6] = (_Float16)(hi.z * sc); f[7] = (_Float16)(hi.w * sc);
            bfrag[m][kt] = f;
        }
    }

    const int arow = cidx >> 2;     // A'[p] = h[p>>2]
    const int row  = grp;           // batch row this lane activates
    float cst = 0.f;

    __syncthreads();

    for (int t = 0; t < T_; ++t) {
        const int rd = t & 1;
        const float2 xv = *reinterpret_cast<const float2*>(&xs[row][2 * t]);
        const _Float16* hb = &h16[rd][0][0];
        const half8 a0 = *reinterpret_cast<const half8*>(hb + arow * 76 + grp * 8);
        const half8 a1 = *reinterpret_cast<const half8*>(hb + arow * 76 + 32 + grp * 8);

        float pre[4];
        #pragma unroll
        for (int m = 0; m < 4; ++m) {
            const float proj = fmaf(xv.y, wi1[m], fmaf(xv.x, wi0[m], bs[m]));
            f32x4 a = {proj, proj, proj, proj};   // bias+x-proj pre-loaded into C
            a = __builtin_amdgcn_mfma_f32_16x16x32_f16(a0, bfrag[m][0], a, 0, 0, 0);
            a = __builtin_amdgcn_mfma_f32_16x16x32_f16(a1, bfrag[m][1], a, 0, 0, 0);
            pre[m] = a[0];                        // STATIC reg 0: batch row = grp
        }

        // pre[m] is already the scaled exp2 argument: Em = 2^pre[m]
        const float Ei = __builtin_amdgcn_exp2f(fminf(pre[0], ECLAMP));  // e^{-ip}
        const float Ef = __builtin_amdgcn_exp2f(fminf(pre[1], ECLAMP));  // e^{-fp}
        const float Eg = __builtin_amdgcn_exp2f(fminf(pre[2], ECLAMP));  // e^{2 gp}
        const float Eo = __builtin_amdgcn_exp2f(fminf(pre[3], ECLAMP));  // e^{-op}

        const float fEf = 1.0f + Ef;
        const float P   = (1.0f + Ei) * (Eg + 1.0f);
        const float r1  = __builtin_amdgcn_rcpf(P * fEf);
        cst = fmaf(cst, P, (Eg - 1.0f) * fEf) * r1;   // = f*c + i*tanh(gp)

        const float Ec = __builtin_amdgcn_exp2f(fminf(K2f * cst, ECLAMP)); // e^{2c}
        const float r2 = __builtin_amdgcn_rcpf((1.0f + Eo) * (Ec + 1.0f));
        const float hv = (Ec - 1.0f) * r2;            // = sigmoid(op)*tanh(c)

        h16[rd ^ 1][row][u] = (_Float16)hv;
        __syncthreads();
    }

    // ---- FC epilogue: h_last is in h16[0] (t=199 wrote buffer 0) ----
    if (tid < 8) {
        const int r = tid & 3;
        const int o = tid >> 2;
        float s = wfc[128 + o];
        #pragma unroll
        for (int k = 0; k < 64; ++k)
            s = fmaf(wfc[o * 64 + k], (float)h16[0][r][k], s);
        out[(size_t)(r0 + r) * 2 + o] = s;
    }
}

extern "C" void kernel_launch(void* const* d_in, const int* in_sizes, int n_in,
                              void* d_out, int out_size, void* d_ws, size_t ws_size,
                              hipStream_t stream) {
    const float* x    = (const float*)d_in[0];
    const float* W_ih = (const float*)d_in[1];
    const float* W_hh = (const float*)d_in[2];
    const float* b_ih = (const float*)d_in[3];
    const float* b_hh = (const float*)d_in[4];
    const float* W_fc = (const float*)d_in[5];
    const float* b_fc = (const float*)d_in[6];
    float* out = (float*)d_out;

    lstm_kernel<<<B_ / 4, 256, 0, stream>>>(x, W_ih, W_hh, b_ih, b_hh, W_fc, b_fc, out);
}

// Round 5
// 127.004 us; speedup vs baseline: 1.6052x; 1.6052x over previous
//
#include <hip/hip_runtime.h>
#include <hip/hip_bf16.h>

// LSTM: B=4096, T=200, I=2, H=64, O=2
// grid = 256 blocks x 256 threads (4 waves, 1 block per CU, 1 wave per SIMD).
// R4 lesson: >1 block/CU convoys on cross-SIMD barriers -> keep 1 block/CU.
// Wave w owns gate-quadrant units [16w,16w+16) for ALL 16 rows: 8 MFMAs/step,
// zero redundancy. Lane (grp,cidx): unit u = 16w+cidx, rows grp*4+{0..3} via
// the four STATIC acc regs (D: row=(l>>4)*4+reg, col=l&15). Each lane runs 4
// independent activation chains -> ILP hides exp2/rcp latency.
// Activation algebra (scales folded into weights at load; i,f,o: -log2e,
// g: 2*log2e):
//   c' = (c*P + (Eg-1)(1+Ef)) * rcp(P*(1+Ef)),  P = (1+Ei)(Eg+1)
//   h  = (Ec-1) * rcp((1+Eo)(Ec+1)),            Ec = 2^(2*log2e*c)
// => 5 exp + 2 rcp per (row,unit). Gate exps unclamped: |pre*scale| <= ~29,
// worst triple-product exponent ~58 < 127. One clamp on the c path.

#define B_ 4096
#define T_ 200

typedef _Float16 half8 __attribute__((ext_vector_type(8)));
typedef float f32x4 __attribute__((ext_vector_type(4)));

#define K1f 1.4426950408889634f   // log2(e)
#define K2f 2.8853900817779268f   // 2*log2(e)

__global__ __launch_bounds__(256) void lstm_kernel(
    const float* __restrict__ x,     // [4096][200][2]
    const float* __restrict__ W_ih,  // [256][2]
    const float* __restrict__ W_hh,  // [256][64]
    const float* __restrict__ b_ih,  // [256]
    const float* __restrict__ b_hh,  // [256]
    const float* __restrict__ W_fc,  // [2][64]
    const float* __restrict__ b_fc,  // [2]
    float* __restrict__ out)         // [4096][2]
{
    __shared__ float xs[16][404];        // x tile (404: float4-aligned, de-conflicted)
    __shared__ _Float16 h16[2][16][72];  // double-buffered h (pad 64->72, 16B-aligned rows)
    __shared__ float wfc[130];           // W_fc (128) + b_fc (2)

    const int tid  = threadIdx.x;
    const int lane = tid & 63;
    const int w    = tid >> 6;      // wave = gate-quadrant 0..3
    const int cidx = lane & 15;
    const int grp  = lane >> 4;
    const int r0   = blockIdx.x * 16;

    // ---- stage x tile (coalesced float4): 16 rows x 100 float4 ----
    for (int i4 = tid; i4 < 1600; i4 += 256) {
        const int row = i4 / 100;
        const int j4  = i4 - row * 100;
        reinterpret_cast<float4*>(&xs[row][0])[j4] =
            reinterpret_cast<const float4*>(x + (size_t)(r0 + row) * 400)[j4];
    }
    // ---- zero h16 (both buffers incl. pad): 2*16*72 f16 = 1152 dwords ----
    for (int i = tid; i < 1152; i += 256)
        reinterpret_cast<unsigned int*>(&h16[0][0][0])[i] = 0u;
    if (tid < 130) wfc[tid] = (tid < 128) ? W_fc[tid] : b_fc[tid - 128];

    // ---- W_hh B-fragments (f16, PRE-SCALED per gate) + x-proj coeffs ----
    // B-frag layout for mfma_f32_16x16x32_f16: lane l -> col = l&15, k = (l>>4)*8 + e
    half8 bfrag[4][2];
    float wi0[4], wi1[4], bs[4];
    const int u = w * 16 + cidx;           // hidden unit owned by this lane
    #pragma unroll
    for (int m = 0; m < 4; ++m) {          // gate: 0=i,1=f,2=g,3=o (PyTorch order)
        const float sc = (m == 2) ? K2f : -K1f;
        const int g = m * 64 + u;
        wi0[m] = W_ih[g * 2 + 0] * sc;
        wi1[m] = W_ih[g * 2 + 1] * sc;
        bs[m]  = (b_ih[g] + b_hh[g]) * sc;
        #pragma unroll
        for (int kt = 0; kt < 2; ++kt) {
            const float* p = W_hh + g * 64 + kt * 32 + grp * 8;
            const float4 lo = reinterpret_cast<const float4*>(p)[0];
            const float4 hi = reinterpret_cast<const float4*>(p)[1];
            half8 f;
            f[0] = (_Float16)(lo.x * sc); f[1] = (_Float16)(lo.y * sc);
            f[2] = (_Float16)(lo.z * sc); f[3] = (_Float16)(lo.w * sc);
            f[4] = (_Float16)(hi.x * sc); f[5] = (_Float16)(hi.y * sc);
            f[6] = (_Float16)(hi.z * sc); f[7] = (_Float16)(hi.w * sc);
            bfrag[m][kt] = f;
        }
    }

    float cst[4] = {0.f, 0.f, 0.f, 0.f};   // cell state: rows grp*4+{0..3}, unit u

    __syncthreads();

    for (int t = 0; t < T_; ++t) {
        const int rd = t & 1;
        const _Float16* hb = &h16[rd][0][0];
        // A-frag: lane l -> A[row=l&15][k=(l>>4)*8+e] (+32 for the second k-tile)
        const half8 a0 = *reinterpret_cast<const half8*>(hb + cidx * 72 + grp * 8);
        const half8 a1 = *reinterpret_cast<const half8*>(hb + cidx * 72 + 32 + grp * 8);

        float2 xv[4];
        #pragma unroll
        for (int r = 0; r < 4; ++r)
            xv[r] = *reinterpret_cast<const float2*>(&xs[grp * 4 + r][2 * t]);

        f32x4 acc[4];
        #pragma unroll
        for (int m = 0; m < 4; ++m) {
            // C pre-loaded with bias + x-projection per row (already gate-scaled)
            f32x4 a = {fmaf(xv[0].y, wi1[m], fmaf(xv[0].x, wi0[m], bs[m])),
                       fmaf(xv[1].y, wi1[m], fmaf(xv[1].x, wi0[m], bs[m])),
                       fmaf(xv[2].y, wi1[m], fmaf(xv[2].x, wi0[m], bs[m])),
                       fmaf(xv[3].y, wi1[m], fmaf(xv[3].x, wi0[m], bs[m]))};
            a = __builtin_amdgcn_mfma_f32_16x16x32_f16(a0, bfrag[m][0], a, 0, 0, 0);
            a = __builtin_amdgcn_mfma_f32_16x16x32_f16(a1, bfrag[m][1], a, 0, 0, 0);
            acc[m] = a;
        }

        // ---- 4 independent activation chains (rows grp*4+r), static reg idx ----
        #pragma unroll
        for (int r = 0; r < 4; ++r) {
            const float Ei = __builtin_amdgcn_exp2f(acc[0][r]);  // e^{-ip}
            const float Ef = __builtin_amdgcn_exp2f(acc[1][r]);  // e^{-fp}
            const float Eg = __builtin_amdgcn_exp2f(acc[2][r]);  // e^{2 gp}
            const float Eo = __builtin_amdgcn_exp2f(acc[3][r]);  // e^{-op}

            const float fEf = 1.0f + Ef;
            const float P   = (1.0f + Ei) * (Eg + 1.0f);
            const float r1  = __builtin_amdgcn_rcpf(P * fEf);
            const float cv  = fmaf(cst[r], P, (Eg - 1.0f) * fEf) * r1;  // f*c + i*tanh(g)
            cst[r] = cv;

            const float Ec = __builtin_amdgcn_exp2f(fminf(K2f * cv, 60.0f));  // e^{2c}
            const float r2 = __builtin_amdgcn_rcpf((1.0f + Eo) * (Ec + 1.0f));
            const float hv = (Ec - 1.0f) * r2;               // sigmoid(op)*tanh(c)

            h16[rd ^ 1][grp * 4 + r][u] = (_Float16)hv;
        }
        __syncthreads();
    }

    // ---- FC epilogue: h_last is in h16[0] (t=199 wrote buffer 0) ----
    if (tid < 32) {
        const int r = tid & 15;
        const int o = tid >> 4;
        float s = wfc[128 + o];
        #pragma unroll
        for (int k = 0; k < 64; ++k)
            s = fmaf(wfc[o * 64 + k], (float)h16[0][r][k], s);
        out[(size_t)(r0 + r) * 2 + o] = s;
    }
}

extern "C" void kernel_launch(void* const* d_in, const int* in_sizes, int n_in,
                              void* d_out, int out_size, void* d_ws, size_t ws_size,
                              hipStream_t stream) {
    const float* x    = (const float*)d_in[0];
    const float* W_ih = (const float*)d_in[1];
    const float* W_hh = (const float*)d_in[2];
    const float* b_ih = (const float*)d_in[3];
    const float* b_hh = (const float*)d_in[4];
    const float* W_fc = (const float*)d_in[5];
    const float* b_fc = (const float*)d_in[6];
    float* out = (float*)d_out;

    lstm_kernel<<<B_ / 16, 256, 0, stream>>>(x, W_ih, W_hh, b_ih, b_hh, W_fc, b_fc, out);
}